// Round 5
// baseline (243.886 us; speedup 1.0000x reference)
//
#include <hip/hip_runtime.h>

#define B_DIM 4
#define T_DIM 96
#define N_DIM 512
#define H_DIM 128
#define NH    (N_DIM * H_DIM)

// d_ws layout (in bf16 shorts):
#define WS_WEXP  0        // [256][128] bf16 row-major
#define WS_WCON  32768    // [128][128] bf16 row-major
#define WS_L     49152    // [96][96]  bf16 row-major: L[t][k] = 0.1*0.9^(t-k), k<=t
#define WS_TOTAL 58368

typedef __attribute__((ext_vector_type(8))) short short8;
typedef __attribute__((ext_vector_type(4))) float f32x4;

__device__ __forceinline__ unsigned short f2b_rh(float f) {
    union { float f; unsigned u; } c; c.f = f;
    return (unsigned short)((c.u + 0x8000u) >> 16);   // round-half-up to bf16
}
// pack two fp32 -> bf16x2 (low = a, high = b): 2 adds + 1 v_perm_b32
__device__ __forceinline__ unsigned pack_bf16_2(float a, float b) {
    union { float f; unsigned u; } ca, cb; ca.f = a; cb.f = b;
    return __builtin_amdgcn_perm(cb.u + 0x8000u, ca.u + 0x8000u, 0x07060302u);
}
__device__ __forceinline__ float u2f(unsigned u) {
    union { unsigned u; float f; } c; c.u = u;
    return c.f;
}

// ---- Prep: fp32 weights -> bf16 in ws; build EMA coefficient matrix L ----
extern "C" __global__ void prep_kernel(const float* __restrict__ Wexp,
                                       const float* __restrict__ Wcon,
                                       unsigned short* __restrict__ ws) {
    int i = blockIdx.x * 256 + threadIdx.x;
    if (i < 32768) {
        ws[WS_WEXP + i] = f2b_rh(Wexp[i]);
    } else if (i < 49152) {
        int j = i - 32768;
        ws[WS_WCON + j] = f2b_rh(Wcon[j]);
    } else if (i < WS_TOTAL) {
        int j = i - 49152;
        int t = j / 96, k = j - t * 96;
        float v = 0.0f;
        if (k <= t) v = 0.1f * __expf((float)(t - k) * -0.1053605157f); // 0.1*0.9^(t-k)
        ws[WS_L + j] = f2b_rh(v);
    }
}

// One 256-thread (4-wave) workgroup per (b, n).  SINGLE 26.6 KB LDS buffer.
// Wave w owns: primary o-tiles {2w,2w+1} (IN REGISTERS, packed bf16),
//              gating o-tiles -> gateT rows h=32w..32w+31 (self-owned, waitcnt not barrier),
//              EMA/gating/GEMM2 h-/o-tiles {2w,2w+1}.
// GEMM1 B-frags straight from GLOBAL (x-tile is L1/L2-hot across the 4 waves).
// gpg aliasing: gateT [128][104] during GEMM1+EMA, then pg [96][136] (barrier between).
// Phases kept SEPARATE (r3 lesson: fusing made wp+wg+eacc+pacc co-live -> spill).
// launch_bounds(256,3): r1/r3/r4 PROVED tighter caps (40/64 regs) force spill
// (+40-240 MB scratch traffic); natural allocation is ~84 regs -> 6 waves/SIMD ->
// 6 blocks/CU, which the 26,624 B LDS now also permits (6x26,624 = 159.7 KB).
// W_con/bias2 loaded after gating, in the final barrier's shadow.
// Biases deferred out of GEMM1; gating bias folded through linear EMA as b*(1-0.9^{t+1}).
// EMA tiles with tt < 2*kf are all-zero (L lower-triangular) -> skipped.
// MFMA 16x16x32 bf16 layouts: A[m=l16][k=q*8+j], B[k=q*8+j][n=l16], D[row=q*4+r][col=l16]
extern "C" __global__ __launch_bounds__(256, 3)
void mamba_fused(const float* __restrict__ x,
                 const unsigned short* __restrict__ ws,
                 const float* __restrict__ b_exp,
                 const float* __restrict__ b_con,
                 float* __restrict__ out)
{
    __shared__ __align__(16) unsigned short gpg[128 * 104];  // gateT [h][t'] s104; later pg [t][h] s136

    const int tid  = threadIdx.x;
    const int wave = tid >> 6;        // 0..3
    const int lane = tid & 63;
    const int q    = lane >> 4;
    const int l16  = lane & 15;

    const int blk = blockIdx.x;
    const int n   = blk & (N_DIM - 1);
    const int b   = blk >> 9;

    const float* xg = x + ((size_t)b * T_DIM * N_DIM + (size_t)n) * H_DIM;

    // ---- W_exp A-fragments (bf16, L2-hot): primary rows {2w,2w+1}*16.., gating +128 ----
    short8 wp[2][4], wg[2][4];
    #pragma unroll
    for (int ot = 0; ot < 2; ++ot) {
        const unsigned short* wrp = ws + WS_WEXP + (size_t)((wave * 2 + ot) * 16 + l16) * H_DIM + q * 8;
        #pragma unroll
        for (int k0 = 0; k0 < 4; ++k0) {
            wp[ot][k0] = *(const short8*)(wrp + k0 * 32);
            wg[ot][k0] = *(const short8*)(wrp + 128 * H_DIM + k0 * 32);
        }
    }

    unsigned pacc[2][6][2];   // primary GEMM1 result, packed bf16x2, NO bias. [ot][mt][2]

    // ---- GEMM1: B-frags from global; primary -> regs, gating -> own gateT rows ----
    #pragma unroll
    for (int mt = 0; mt < 6; ++mt) {
        const float* xrow = xg + (size_t)(mt * 16 + l16) * NH + q * 8;
        short8 bfr[4];
        #pragma unroll
        for (int k0 = 0; k0 < 4; ++k0) {
            float4 v0 = *(const float4*)(xrow + k0 * 32);
            float4 v1 = *(const float4*)(xrow + k0 * 32 + 4);
            union { unsigned u[4]; short8 s; } p;
            p.u[0] = pack_bf16_2(v0.x, v0.y);
            p.u[1] = pack_bf16_2(v0.z, v0.w);
            p.u[2] = pack_bf16_2(v1.x, v1.y);
            p.u[3] = pack_bf16_2(v1.z, v1.w);
            bfr[k0] = p.s;
        }
        f32x4 ap0 = {0.f,0.f,0.f,0.f}, ap1 = {0.f,0.f,0.f,0.f};
        f32x4 ag0 = {0.f,0.f,0.f,0.f}, ag1 = {0.f,0.f,0.f,0.f};
        #pragma unroll
        for (int k0 = 0; k0 < 4; ++k0) {
            ap0 = __builtin_amdgcn_mfma_f32_16x16x32_bf16(wp[0][k0], bfr[k0], ap0, 0, 0, 0);
            ap1 = __builtin_amdgcn_mfma_f32_16x16x32_bf16(wp[1][k0], bfr[k0], ap1, 0, 0, 0);
            ag0 = __builtin_amdgcn_mfma_f32_16x16x32_bf16(wg[0][k0], bfr[k0], ag0, 0, 0, 0);
            ag1 = __builtin_amdgcn_mfma_f32_16x16x32_bf16(wg[1][k0], bfr[k0], ag1, 0, 0, 0);
        }
        pacc[0][mt][0] = pack_bf16_2(ap0[0], ap0[1]);
        pacc[0][mt][1] = pack_bf16_2(ap0[2], ap0[3]);
        pacc[1][mt][0] = pack_bf16_2(ap1[0], ap1[1]);
        pacc[1][mt][1] = pack_bf16_2(ap1[2], ap1[3]);
        // gating D-frags -> gateT[h][t'] (stride 104), rows h=32w..32w+31 owned by this wave
        unsigned short* gr0 = &gpg[((wave * 2 + 0) * 16 + q * 4) * 104 + mt * 16 + l16];
        gr0[0]       = f2b_rh(ag0[0]);
        gr0[104]     = f2b_rh(ag0[1]);
        gr0[2 * 104] = f2b_rh(ag0[2]);
        gr0[3 * 104] = f2b_rh(ag0[3]);
        unsigned short* gr1 = &gpg[((wave * 2 + 1) * 16 + q * 4) * 104 + mt * 16 + l16];
        gr1[0]       = f2b_rh(ag1[0]);
        gr1[104]     = f2b_rh(ag1[1]);
        gr1[2 * 104] = f2b_rh(ag1[2]);
        gr1[3 * 104] = f2b_rh(ag1[3]);
    }

    // Wave reads back only the gateT rows IT wrote: drain LDS queue, fence scheduler.
    asm volatile("s_waitcnt lgkmcnt(0)" ::: "memory");
    __builtin_amdgcn_sched_barrier(0);

    // ---- EMA via MFMA: S^T[h][t] = G^T (A, m=h) x L^T (B, n=t), K=96, triangular-pruned ----
    f32x4 eacc[2][6];
    #pragma unroll
    for (int ht = 0; ht < 2; ++ht)
        #pragma unroll
        for (int tt = 0; tt < 6; ++tt)
            eacc[ht][tt] = (f32x4){0.f, 0.f, 0.f, 0.f};
    {
        const unsigned short* wsL = ws + WS_L;
        #pragma unroll
        for (int kf = 0; kf < 3; ++kf) {
            short8 af0 = *(const short8*)&gpg[((wave * 2 + 0) * 16 + l16) * 104 + kf * 32 + q * 8];
            short8 af1 = *(const short8*)&gpg[((wave * 2 + 1) * 16 + l16) * 104 + kf * 32 + q * 8];
            #pragma unroll
            for (int tt = 0; tt < 6; ++tt) {
                if (tt < 2 * kf) continue;   // L[t][k]==0 for whole tile (k > t)
                short8 bf = *(const short8*)(wsL + (size_t)(tt * 16 + l16) * 96 + kf * 32 + q * 8);
                eacc[0][tt] = __builtin_amdgcn_mfma_f32_16x16x32_bf16(af0, bf, eacc[0][tt], 0, 0, 0);
                eacc[1][tt] = __builtin_amdgcn_mfma_f32_16x16x32_bf16(af1, bf, eacc[1][tt], 0, 0, 0);
            }
        }
    }

    // ---- gating biases (4 scalar-ish loads; L2-hot) ----
    float4 bp[2], bgv[2];
    #pragma unroll
    for (int ot = 0; ot < 2; ++ot) {
        const int o = (wave * 2 + ot) * 16;
        bp[ot]  = *(const float4*)(b_exp + o + q * 4);
        bgv[ot] = *(const float4*)(b_exp + 128 + o + q * 4);
    }
    // bias-fold constants 1-0.9^{t+1}, t = tt*16+l16 (hoisted: 6 exps, not 12)
    float cfac[6];
    #pragma unroll
    for (int tt = 0; tt < 6; ++tt)
        cfac[tt] = 1.0f - __expf((float)(tt * 16 + l16 + 1) * -0.1053605157f);

    __syncthreads();   // all waves done with gateT reads -> safe to overwrite gpg with pg

    // ---- gating: sigmoid(EMA + bg*cfac) * (prim_reg + bp) -> pg [t][h] stride 136 ----
    #pragma unroll
    for (int ot = 0; ot < 2; ++ot) {
        const int hb = (wave * 2 + ot) * 16 + q * 4;
        #pragma unroll
        for (int tt = 0; tt < 6; ++tt) {
            const int t = tt * 16 + l16;
            f32x4 s = eacc[ot][tt];
            float sg0 = __fdividef(1.f, 1.f + __expf(-(s[0] + bgv[ot].x * cfac[tt])));
            float sg1 = __fdividef(1.f, 1.f + __expf(-(s[1] + bgv[ot].y * cfac[tt])));
            float sg2 = __fdividef(1.f, 1.f + __expf(-(s[2] + bgv[ot].z * cfac[tt])));
            float sg3 = __fdividef(1.f, 1.f + __expf(-(s[3] + bgv[ot].w * cfac[tt])));
            unsigned u0 = pacc[ot][tt][0], u1 = pacc[ot][tt][1];
            float p0 = (u2f(u0 << 16)         + bp[ot].x) * sg0;
            float p1 = (u2f(u0 & 0xffff0000u) + bp[ot].y) * sg1;
            float p2 = (u2f(u1 << 16)         + bp[ot].z) * sg2;
            float p3 = (u2f(u1 & 0xffff0000u) + bp[ot].w) * sg3;
            union { unsigned u[2]; ushort4 s; } pk;
            pk.u[0] = pack_bf16_2(p0, p1);
            pk.u[1] = pack_bf16_2(p2, p3);
            *(ushort4*)&gpg[t * 136 + hb] = pk.s;
        }
    }

    // ---- W_con frags + bias2: loaded in the barrier's shadow (keeps gating peak low) ----
    short8 wc[2][4];
    float4 bias2[2];
    #pragma unroll
    for (int ot = 0; ot < 2; ++ot) {
        const int o = (wave * 2 + ot) * 16;
        const unsigned short* wrc = ws + WS_WCON + (size_t)(o + l16) * H_DIM + q * 8;
        #pragma unroll
        for (int k0 = 0; k0 < 4; ++k0)
            wc[ot][k0] = *(const short8*)(wrc + k0 * 32);
        bias2[ot] = *(const float4*)(b_con + o + q * 4);
    }
    __syncthreads();   // cross-wave handoff: pg B-frags span all h

    // ---- GEMM2: out[o][t] = Wc @ pg^T + b ----
    float* og = out + ((size_t)b * T_DIM * N_DIM + (size_t)n) * H_DIM;
    #pragma unroll
    for (int mt = 0; mt < 6; ++mt) {
        short8 bfr[4];
        const unsigned short* prow = &gpg[(mt * 16 + l16) * 136];
        #pragma unroll
        for (int k0 = 0; k0 < 4; ++k0)
            bfr[k0] = *(const short8*)(prow + k0 * 32 + q * 8);
        const int t = mt * 16 + l16;
        #pragma unroll
        for (int ot = 0; ot < 2; ++ot) {
            f32x4 acc = {0.f, 0.f, 0.f, 0.f};
            #pragma unroll
            for (int k0 = 0; k0 < 4; ++k0)
                acc = __builtin_amdgcn_mfma_f32_16x16x32_bf16(wc[ot][k0], bfr[k0], acc, 0, 0, 0);
            const int o = (wave * 2 + ot) * 16 + q * 4;
            float4 v;
            v.x = acc[0] + bias2[ot].x;
            v.y = acc[1] + bias2[ot].y;
            v.z = acc[2] + bias2[ot].z;
            v.w = acc[3] + bias2[ot].w;
            *(float4*)(og + (size_t)t * NH + o) = v;
        }
    }
}

extern "C" void kernel_launch(void* const* d_in, const int* in_sizes, int n_in,
                              void* d_out, int out_size, void* d_ws, size_t ws_size,
                              hipStream_t stream) {
    const float* x     = (const float*)d_in[0];
    const float* W_exp = (const float*)d_in[1];
    const float* b_exp = (const float*)d_in[2];
    const float* W_con = (const float*)d_in[3];
    const float* b_con = (const float*)d_in[4];
    float* out = (float*)d_out;
    unsigned short* ws = (unsigned short*)d_ws;

    hipLaunchKernelGGL(prep_kernel, dim3(WS_TOTAL / 256), dim3(256), 0, stream,
                       W_exp, W_con, ws);
    hipLaunchKernelGGL(mamba_fused, dim3(B_DIM * N_DIM), dim3(256), 0, stream,
                       x, ws, b_exp, b_con, out);
}

// Round 6
// 232.945 us; speedup vs baseline: 1.0470x; 1.0470x over previous
//
#include <hip/hip_runtime.h>

#define B_DIM 4
#define T_DIM 96
#define N_DIM 512
#define H_DIM 128
#define NH    (N_DIM * H_DIM)

// d_ws layout (in bf16 shorts):
#define WS_WEXP  0        // [256][128] bf16 row-major
#define WS_WCON  32768    // [128][128] bf16 row-major
#define WS_L     49152    // [96][96]  bf16 row-major: L[t][k] = 0.1*0.9^(t-k), k<=t
#define WS_TOTAL 58368

#define XS 132   // xpg stride in shorts: b128 frag reads land 2-way (2*l16 distinct banks)
#define GS 100   // gateT stride in shorts: scalar transpose writes are a 32-bank bijection

typedef __attribute__((ext_vector_type(8))) short short8;
typedef __attribute__((ext_vector_type(4))) float f32x4;

__device__ __forceinline__ unsigned short f2b_rh(float f) {
    union { float f; unsigned u; } c; c.f = f;
    return (unsigned short)((c.u + 0x8000u) >> 16);   // round-half-up to bf16
}
// pack two fp32 -> bf16x2 (low = a, high = b): 2 adds + 1 v_perm_b32
__device__ __forceinline__ unsigned pack_bf16_2(float a, float b) {
    union { float f; unsigned u; } ca, cb; ca.f = a; cb.f = b;
    return __builtin_amdgcn_perm(cb.u + 0x8000u, ca.u + 0x8000u, 0x07060302u);
}
__device__ __forceinline__ float u2f(unsigned u) {
    union { unsigned u; float f; } c; c.u = u;
    return c.f;
}

// ---- Prep: fp32 weights -> bf16 in ws; build EMA coefficient matrix L ----
extern "C" __global__ void prep_kernel(const float* __restrict__ Wexp,
                                       const float* __restrict__ Wcon,
                                       unsigned short* __restrict__ ws) {
    int i = blockIdx.x * 256 + threadIdx.x;
    if (i < 32768) {
        ws[WS_WEXP + i] = f2b_rh(Wexp[i]);
    } else if (i < 49152) {
        int j = i - 32768;
        ws[WS_WCON + j] = f2b_rh(Wcon[j]);
    } else if (i < WS_TOTAL) {
        int j = i - 49152;
        int t = j / 96, k = j - t * 96;
        float v = 0.0f;
        if (k <= t) v = 0.1f * __expf((float)(t - k) * -0.1053605157f); // 0.1*0.9^(t-k)
        ws[WS_L + j] = f2b_rh(v);
    }
}

// One 512-thread (8-wave) workgroup per (b, n).
// KEY (r5 lesson): VGPR granule is 64 — >64 regs caps the chip at 16 waves/CU no matter
// what LDS does. 8-wave blocks let each wave own ONE prim + ONE gate o-tile, and GEMM1
// runs as two sequential passes (gate-W then prim-W, 16 regs reused; bfr re-read from
// LDS) -> live peak ~58 regs < 64. LDS is per-BLOCK: x-stage (25.3K, r2's proven win)
// + gateT (25.6K) = 50.9K -> 3 blocks/CU = 24 waves/CU (2x r2's 12).
// Wave w owns: prim o-tile w (pacc regs), gate o-tile w -> gateT rows h=16w..16w+15
// (self-owned: waitcnt not barrier), EMA/gating h-tile w, GEMM2 o-tile w.
// gpg aliasing: xpg holds x bf16 [96][XS] during GEMM1, then pg [96][XS] (barrier between).
// Biases deferred out of GEMM1; gating bias folded through linear EMA as b*(1-0.9^{t+1}).
// EMA tiles with tt < 2*kf are all-zero (L lower-triangular) -> skipped.
// MFMA 16x16x32 bf16 layouts: A[m=l16][k=q*8+j], B[k=q*8+j][n=l16], D[row=q*4+r][col=l16]
extern "C" __global__ __launch_bounds__(512, 4)
void mamba_fused(const float* __restrict__ x,
                 const unsigned short* __restrict__ ws,
                 const float* __restrict__ b_exp,
                 const float* __restrict__ b_con,
                 float* __restrict__ out)
{
    __shared__ __align__(16) unsigned short xpg[96 * XS];     // x bf16 [t][h]; later pg [t][h]
    __shared__ __align__(16) unsigned short gateT[128 * GS];  // G^T [h][t']

    const int tid  = threadIdx.x;
    const int wave = tid >> 6;        // 0..7
    const int lane = tid & 63;
    const int q    = lane >> 4;
    const int l16  = lane & 15;

    const int blk = blockIdx.x;
    const int n   = blk & (N_DIM - 1);
    const int b   = blk >> 9;

    const float* xg = x + ((size_t)b * T_DIM * N_DIM + (size_t)n) * H_DIM;

    // ---- Stage x-tile -> bf16 LDS, cooperatively (512 threads: 6 float4 each) ----
    {
        const int rt = tid >> 5;      // 0..15
        const int c  = tid & 31;      // 32 threads x 4 floats = full 128-col row
        #pragma unroll
        for (int i = 0; i < 6; ++i) {
            const int r = i * 16 + rt;
            float4 v = *(const float4*)(xg + (size_t)r * NH + c * 4);
            union { unsigned u[2]; ushort4 s; } pk;
            pk.u[0] = pack_bf16_2(v.x, v.y);
            pk.u[1] = pack_bf16_2(v.z, v.w);
            *(ushort4*)&xpg[r * XS + c * 4] = pk.s;
        }
    }
    __syncthreads();   // x-tile staged

    // ---- GEMM1 pass A (gate): o-tile 128+16w -> gateT rows h=16w..16w+15 ----
    {
        short8 wgf[4];
        const unsigned short* wr = ws + WS_WEXP + (size_t)(128 + wave * 16 + l16) * H_DIM + q * 8;
        #pragma unroll
        for (int k0 = 0; k0 < 4; ++k0)
            wgf[k0] = *(const short8*)(wr + k0 * 32);
        #pragma unroll
        for (int mt = 0; mt < 6; ++mt) {
            short8 bfr[4];
            #pragma unroll
            for (int k0 = 0; k0 < 4; ++k0)
                bfr[k0] = *(const short8*)&xpg[(mt * 16 + l16) * XS + k0 * 32 + q * 8];
            f32x4 ag = {0.f, 0.f, 0.f, 0.f};
            #pragma unroll
            for (int k0 = 0; k0 < 4; ++k0)
                ag = __builtin_amdgcn_mfma_f32_16x16x32_bf16(wgf[k0], bfr[k0], ag, 0, 0, 0);
            unsigned short* gr = &gateT[(wave * 16 + q * 4) * GS + mt * 16 + l16];
            gr[0]      = f2b_rh(ag[0]);
            gr[GS]     = f2b_rh(ag[1]);
            gr[2 * GS] = f2b_rh(ag[2]);
            gr[3 * GS] = f2b_rh(ag[3]);
        }
    }

    // ---- GEMM1 pass B (primary): o-tile 16w -> pacc registers (packed bf16) ----
    unsigned pacc[6][2];
    {
        short8 wpf[4];
        const unsigned short* wr = ws + WS_WEXP + (size_t)(wave * 16 + l16) * H_DIM + q * 8;
        #pragma unroll
        for (int k0 = 0; k0 < 4; ++k0)
            wpf[k0] = *(const short8*)(wr + k0 * 32);
        #pragma unroll
        for (int mt = 0; mt < 6; ++mt) {
            short8 bfr[4];
            #pragma unroll
            for (int k0 = 0; k0 < 4; ++k0)
                bfr[k0] = *(const short8*)&xpg[(mt * 16 + l16) * XS + k0 * 32 + q * 8];
            f32x4 ap = {0.f, 0.f, 0.f, 0.f};
            #pragma unroll
            for (int k0 = 0; k0 < 4; ++k0)
                ap = __builtin_amdgcn_mfma_f32_16x16x32_bf16(wpf[k0], bfr[k0], ap, 0, 0, 0);
            pacc[mt][0] = pack_bf16_2(ap[0], ap[1]);
            pacc[mt][1] = pack_bf16_2(ap[2], ap[3]);
        }
    }

    // Wave reads back only the gateT rows IT wrote: drain LDS queue, fence scheduler.
    asm volatile("s_waitcnt lgkmcnt(0)" ::: "memory");
    __builtin_amdgcn_sched_barrier(0);

    // ---- EMA via MFMA: S^T[h][t] = G^T (A, m=h) x L^T (B, n=t), K=96, triangular-pruned ----
    f32x4 eacc[6];
    #pragma unroll
    for (int tt = 0; tt < 6; ++tt)
        eacc[tt] = (f32x4){0.f, 0.f, 0.f, 0.f};
    {
        const unsigned short* wsL = ws + WS_L;
        #pragma unroll
        for (int kf = 0; kf < 3; ++kf) {
            short8 af = *(const short8*)&gateT[(wave * 16 + l16) * GS + kf * 32 + q * 8];
            #pragma unroll
            for (int tt = 0; tt < 6; ++tt) {
                if (tt < 2 * kf) continue;   // L[t][k]==0 for whole tile (k > t)
                short8 bf = *(const short8*)(wsL + (size_t)(tt * 16 + l16) * 96 + kf * 32 + q * 8);
                eacc[tt] = __builtin_amdgcn_mfma_f32_16x16x32_bf16(af, bf, eacc[tt], 0, 0, 0);
            }
        }
    }

    // ---- gating biases (L2-hot) ----
    float4 bp  = *(const float4*)(b_exp + wave * 16 + q * 4);
    float4 bgv = *(const float4*)(b_exp + 128 + wave * 16 + q * 4);

    __syncthreads();   // all waves done reading xpg (GEMM1) -> safe to overwrite with pg

    // ---- gating: sigmoid(EMA + bg*(1-0.9^{t+1})) * (prim_reg + bp) -> pg [t][h] ----
    {
        const int hb = wave * 16 + q * 4;
        #pragma unroll
        for (int tt = 0; tt < 6; ++tt) {
            const int t = tt * 16 + l16;
            const float c = 1.0f - __expf((float)(t + 1) * -0.1053605157f); // 1-0.9^{t+1}
            f32x4 s = eacc[tt];
            float sg0 = __fdividef(1.f, 1.f + __expf(-(s[0] + bgv.x * c)));
            float sg1 = __fdividef(1.f, 1.f + __expf(-(s[1] + bgv.y * c)));
            float sg2 = __fdividef(1.f, 1.f + __expf(-(s[2] + bgv.z * c)));
            float sg3 = __fdividef(1.f, 1.f + __expf(-(s[3] + bgv.w * c)));
            unsigned u0 = pacc[tt][0], u1 = pacc[tt][1];
            float p0 = (u2f(u0 << 16)         + bp.x) * sg0;
            float p1 = (u2f(u0 & 0xffff0000u) + bp.y) * sg1;
            float p2 = (u2f(u1 << 16)         + bp.z) * sg2;
            float p3 = (u2f(u1 & 0xffff0000u) + bp.w) * sg3;
            union { unsigned u[2]; ushort4 s; } pk;
            pk.u[0] = pack_bf16_2(p0, p1);
            pk.u[1] = pack_bf16_2(p2, p3);
            *(ushort4*)&xpg[t * XS + hb] = pk.s;
        }
    }

    // ---- W_con frag + bias2: loaded in the barrier's shadow ----
    short8 wc[4];
    float4 bias2;
    {
        const unsigned short* wrc = ws + WS_WCON + (size_t)(wave * 16 + l16) * H_DIM + q * 8;
        #pragma unroll
        for (int k0 = 0; k0 < 4; ++k0)
            wc[k0] = *(const short8*)(wrc + k0 * 32);
        bias2 = *(const float4*)(b_con + wave * 16 + q * 4);
    }
    __syncthreads();   // cross-wave handoff: pg B-frags span all h

    // ---- GEMM2: out[o][t] = Wc @ pg^T + b ----
    float* og = out + ((size_t)b * T_DIM * N_DIM + (size_t)n) * H_DIM;
    #pragma unroll
    for (int mt = 0; mt < 6; ++mt) {
        short8 bfr[4];
        const unsigned short* prow = &xpg[(mt * 16 + l16) * XS];
        #pragma unroll
        for (int k0 = 0; k0 < 4; ++k0)
            bfr[k0] = *(const short8*)(prow + k0 * 32 + q * 8);
        f32x4 acc = {0.f, 0.f, 0.f, 0.f};
        #pragma unroll
        for (int k0 = 0; k0 < 4; ++k0)
            acc = __builtin_amdgcn_mfma_f32_16x16x32_bf16(wc[k0], bfr[k0], acc, 0, 0, 0);
        const int t = mt * 16 + l16;
        float4 v;
        v.x = acc[0] + bias2.x;
        v.y = acc[1] + bias2.y;
        v.z = acc[2] + bias2.z;
        v.w = acc[3] + bias2.w;
        *(float4*)(og + (size_t)t * NH + wave * 16 + q * 4) = v;
    }
}

extern "C" void kernel_launch(void* const* d_in, const int* in_sizes, int n_in,
                              void* d_out, int out_size, void* d_ws, size_t ws_size,
                              hipStream_t stream) {
    const float* x     = (const float*)d_in[0];
    const float* W_exp = (const float*)d_in[1];
    const float* b_exp = (const float*)d_in[2];
    const float* W_con = (const float*)d_in[3];
    const float* b_con = (const float*)d_in[4];
    float* out = (float*)d_out;
    unsigned short* ws = (unsigned short*)d_ws;

    hipLaunchKernelGGL(prep_kernel, dim3(WS_TOTAL / 256), dim3(256), 0, stream,
                       W_exp, W_con, ws);
    hipLaunchKernelGGL(mamba_fused, dim3(B_DIM * N_DIM), dim3(512), 0, stream,
                       x, ws, b_exp, b_con, out);
}

// Round 7
// 211.713 us; speedup vs baseline: 1.1520x; 1.1003x over previous
//
#include <hip/hip_runtime.h>

#define B_DIM 4
#define T_DIM 96
#define N_DIM 512
#define H_DIM 128
#define NH    (N_DIM * H_DIM)

// d_ws layout (in bf16 shorts):
#define WS_WEXP  0        // [256][128] bf16 row-major
#define WS_WCON  32768    // [128][128] bf16 row-major
#define WS_L     49152    // [96][96]  bf16 row-major: L[t][k] = 0.1*0.9^(t-k), k<=t
#define WS_TOTAL 58368

#define XS 132   // x-window / pg stride in shorts (r6-verified: zero bank conflicts)
#define GS 100   // gateT stride in shorts (r6-verified: zero bank conflicts)

typedef __attribute__((ext_vector_type(8))) short short8;
typedef __attribute__((ext_vector_type(4))) float f32x4;

__device__ __forceinline__ unsigned short f2b_rh(float f) {
    union { float f; unsigned u; } c; c.f = f;
    return (unsigned short)((c.u + 0x8000u) >> 16);   // round-half-up to bf16
}
// pack two fp32 -> bf16x2 (low = a, high = b): 2 adds + 1 v_perm_b32
__device__ __forceinline__ unsigned pack_bf16_2(float a, float b) {
    union { float f; unsigned u; } ca, cb; ca.f = a; cb.f = b;
    return __builtin_amdgcn_perm(cb.u + 0x8000u, ca.u + 0x8000u, 0x07060302u);
}
__device__ __forceinline__ float u2f(unsigned u) {
    union { unsigned u; float f; } c; c.u = u;
    return c.f;
}

// LDS-only barrier: drains ds ops, does NOT drain vmcnt -> global prefetches
// stay in flight across it (the m201/HK pattern; __syncthreads would emit
// s_waitcnt vmcnt(0) and kill the pipeline).
#define BAR_LGKM()  do {                                        \
    asm volatile("s_waitcnt lgkmcnt(0)" ::: "memory");          \
    __builtin_amdgcn_sched_barrier(0);                          \
    __builtin_amdgcn_s_barrier();                               \
    __builtin_amdgcn_sched_barrier(0);                          \
} while (0)

// ---- Prep: fp32 weights -> bf16 in ws; build EMA coefficient matrix L ----
extern "C" __global__ void prep_kernel(const float* __restrict__ Wexp,
                                       const float* __restrict__ Wcon,
                                       unsigned short* __restrict__ ws) {
    int i = blockIdx.x * 256 + threadIdx.x;
    if (i < 32768) {
        ws[WS_WEXP + i] = f2b_rh(Wexp[i]);
    } else if (i < 49152) {
        int j = i - 32768;
        ws[WS_WCON + j] = f2b_rh(Wcon[j]);
    } else if (i < WS_TOTAL) {
        int j = i - 49152;
        int t = j / 96, k = j - t * 96;
        float v = 0.0f;
        if (k <= t) v = 0.1f * __expf((float)(t - k) * -0.1053605157f); // 0.1*0.9^(t-k)
        ws[WS_L + j] = f2b_rh(v);
    }
}

// One 256-thread (4-wave) workgroup per (b, n).  LDS = 34.0 KB -> 4 blocks/CU.
// r2's verified shape (wave w owns prim o-tiles {2w,2w+1} in regs, gate o-tiles ->
// self-owned gateT rows, EMA/gating/GEMM2 h-tiles {2w,2w+1}; 16 MFMA per B-frag read)
// PLUS a software-pipelined stage<->GEMM1: 2-tile rolling x window xw[2][16][XS];
// per mt: pack+ds_write tile mt, issue global loads for mt+2 (in flight across the
// barrier), lgkm-only s_barrier, ds_read + 16 MFMA.  No vmcnt drain anywhere.
// Window safety: reads of slot s are lgkm-drained before BARRIER_{mt+1}; the next
// write of slot s happens after BARRIER_{mt+1} -> no WAR race.
// gpg aliasing: gateT [128][GS] during GEMM1+EMA, then pg [96][XS] (barrier between).
// Biases deferred out of GEMM1; gating bias folded through linear EMA as b*(1-0.9^{t+1}).
// EMA tiles with tt < 2*kf are all-zero (L lower-triangular) -> skipped.
// MFMA 16x16x32 bf16 layouts: A[m=l16][k=q*8+j], B[k=q*8+j][n=l16], D[row=q*4+r][col=l16]
extern "C" __global__ __launch_bounds__(256, 3)
void mamba_fused(const float* __restrict__ x,
                 const unsigned short* __restrict__ ws,
                 const float* __restrict__ b_exp,
                 const float* __restrict__ b_con,
                 float* __restrict__ out)
{
    __shared__ __align__(16) unsigned short xw[2][16 * XS];  // rolling 2-tile x window (bf16)
    __shared__ __align__(16) unsigned short gpg[128 * GS];   // gateT [h][GS]; later pg [t][XS]

    const int tid  = threadIdx.x;
    const int wave = tid >> 6;        // 0..3
    const int lane = tid & 63;
    const int q    = lane >> 4;
    const int l16  = lane & 15;

    const int blk = blockIdx.x;
    const int n   = blk & (N_DIM - 1);
    const int b   = blk >> 9;

    const float* xg = x + ((size_t)b * T_DIM * N_DIM + (size_t)n) * H_DIM;

    // stage mapping: 256 threads cover one 16x128 tile; 2 float4 per thread
    const int srow = tid >> 4;          // 0..15
    const int scol = (tid & 15) * 8;    // float col: 0,8,...,120

    // ---- prologue x loads (HBM = longest latency: issue FIRST) ----
    float4 vx[2][2];
    {
        const float* xr0 = xg + (size_t)srow * NH + scol;          // mt0
        vx[0][0] = *(const float4*)xr0;
        vx[0][1] = *(const float4*)(xr0 + 4);
        const float* xr1 = xg + (size_t)(16 + srow) * NH + scol;   // mt1
        vx[1][0] = *(const float4*)xr1;
        vx[1][1] = *(const float4*)(xr1 + 4);
    }

    // ---- W_exp A-fragments (L2-hot; latency hides under x-wait) ----
    short8 wp[2][4], wg[2][4];
    #pragma unroll
    for (int ot = 0; ot < 2; ++ot) {
        const unsigned short* wrp = ws + WS_WEXP + (size_t)((wave * 2 + ot) * 16 + l16) * H_DIM + q * 8;
        #pragma unroll
        for (int k0 = 0; k0 < 4; ++k0) {
            wp[ot][k0] = *(const short8*)(wrp + k0 * 32);
            wg[ot][k0] = *(const short8*)(wrp + 128 * H_DIM + k0 * 32);
        }
    }

    unsigned pacc[2][6][2];   // primary GEMM1 result, packed bf16x2, NO bias. [ot][mt][2]

    // ---- Pipelined stage + GEMM1 (fully unrolled -> all vx/pacc indices static) ----
    #pragma unroll
    for (int mt = 0; mt < 6; ++mt) {
        const int sl = mt & 1;
        // pack + window write of tile mt
        {
            union { unsigned u[2]; ushort4 s; } p0, p1;
            p0.u[0] = pack_bf16_2(vx[sl][0].x, vx[sl][0].y);
            p0.u[1] = pack_bf16_2(vx[sl][0].z, vx[sl][0].w);
            p1.u[0] = pack_bf16_2(vx[sl][1].x, vx[sl][1].y);
            p1.u[1] = pack_bf16_2(vx[sl][1].z, vx[sl][1].w);
            *(ushort4*)&xw[sl][srow * XS + scol]     = p0.s;
            *(ushort4*)&xw[sl][srow * XS + scol + 4] = p1.s;
        }
        // prefetch tile mt+2 (stays in flight across the barrier)
        if (mt + 2 < 6) {
            const float* xr = xg + (size_t)((mt + 2) * 16 + srow) * NH + scol;
            vx[sl][0] = *(const float4*)xr;
            vx[sl][1] = *(const float4*)(xr + 4);
        }
        BAR_LGKM();   // tile mt visible to all waves; vmem prefetches NOT drained

        // GEMM1 on tile mt: 4 ds_read_b128 -> 16 MFMA
        short8 bfr[4];
        #pragma unroll
        for (int k0 = 0; k0 < 4; ++k0)
            bfr[k0] = *(const short8*)&xw[sl][l16 * XS + k0 * 32 + q * 8];
        f32x4 ap0 = {0.f,0.f,0.f,0.f}, ap1 = {0.f,0.f,0.f,0.f};
        f32x4 ag0 = {0.f,0.f,0.f,0.f}, ag1 = {0.f,0.f,0.f,0.f};
        #pragma unroll
        for (int k0 = 0; k0 < 4; ++k0) {
            ap0 = __builtin_amdgcn_mfma_f32_16x16x32_bf16(wp[0][k0], bfr[k0], ap0, 0, 0, 0);
            ap1 = __builtin_amdgcn_mfma_f32_16x16x32_bf16(wp[1][k0], bfr[k0], ap1, 0, 0, 0);
            ag0 = __builtin_amdgcn_mfma_f32_16x16x32_bf16(wg[0][k0], bfr[k0], ag0, 0, 0, 0);
            ag1 = __builtin_amdgcn_mfma_f32_16x16x32_bf16(wg[1][k0], bfr[k0], ag1, 0, 0, 0);
        }
        pacc[0][mt][0] = pack_bf16_2(ap0[0], ap0[1]);
        pacc[0][mt][1] = pack_bf16_2(ap0[2], ap0[3]);
        pacc[1][mt][0] = pack_bf16_2(ap1[0], ap1[1]);
        pacc[1][mt][1] = pack_bf16_2(ap1[2], ap1[3]);
        // gating D-frags -> gateT[h][t'] rows h=32w..32w+31 (self-owned)
        unsigned short* gr0 = &gpg[((wave * 2 + 0) * 16 + q * 4) * GS + mt * 16 + l16];
        gr0[0]      = f2b_rh(ag0[0]);
        gr0[GS]     = f2b_rh(ag0[1]);
        gr0[2 * GS] = f2b_rh(ag0[2]);
        gr0[3 * GS] = f2b_rh(ag0[3]);
        unsigned short* gr1 = &gpg[((wave * 2 + 1) * 16 + q * 4) * GS + mt * 16 + l16];
        gr1[0]      = f2b_rh(ag1[0]);
        gr1[GS]     = f2b_rh(ag1[1]);
        gr1[2 * GS] = f2b_rh(ag1[2]);
        gr1[3 * GS] = f2b_rh(ag1[3]);
    }

    // Wave reads back only the gateT rows IT wrote: drain LDS queue, fence scheduler.
    asm volatile("s_waitcnt lgkmcnt(0)" ::: "memory");
    __builtin_amdgcn_sched_barrier(0);

    // ---- EMA via MFMA: S^T[h][t] = G^T (A, m=h) x L^T (B, n=t), K=96, triangular-pruned ----
    f32x4 eacc[2][6];
    #pragma unroll
    for (int ht = 0; ht < 2; ++ht)
        #pragma unroll
        for (int tt = 0; tt < 6; ++tt)
            eacc[ht][tt] = (f32x4){0.f, 0.f, 0.f, 0.f};
    {
        const unsigned short* wsL = ws + WS_L;
        #pragma unroll
        for (int kf = 0; kf < 3; ++kf) {
            short8 af0 = *(const short8*)&gpg[((wave * 2 + 0) * 16 + l16) * GS + kf * 32 + q * 8];
            short8 af1 = *(const short8*)&gpg[((wave * 2 + 1) * 16 + l16) * GS + kf * 32 + q * 8];
            #pragma unroll
            for (int tt = 0; tt < 6; ++tt) {
                if (tt < 2 * kf) continue;   // L[t][k]==0 for whole tile (k > t)
                short8 bf = *(const short8*)(wsL + (size_t)(tt * 16 + l16) * 96 + kf * 32 + q * 8);
                eacc[0][tt] = __builtin_amdgcn_mfma_f32_16x16x32_bf16(af0, bf, eacc[0][tt], 0, 0, 0);
                eacc[1][tt] = __builtin_amdgcn_mfma_f32_16x16x32_bf16(af1, bf, eacc[1][tt], 0, 0, 0);
            }
        }
    }

    // ---- gating biases + fold constants (in the barrier's shadow) ----
    float4 bp[2], bgv[2];
    #pragma unroll
    for (int ot = 0; ot < 2; ++ot) {
        const int o = (wave * 2 + ot) * 16;
        bp[ot]  = *(const float4*)(b_exp + o + q * 4);
        bgv[ot] = *(const float4*)(b_exp + 128 + o + q * 4);
    }
    float cfac[6];
    #pragma unroll
    for (int tt = 0; tt < 6; ++tt)
        cfac[tt] = 1.0f - __expf((float)(tt * 16 + l16 + 1) * -0.1053605157f); // 1-0.9^{t+1}

    BAR_LGKM();   // all waves done with gateT reads -> safe to overwrite gpg with pg

    // ---- gating: sigmoid(EMA + bg*cfac) * (prim_reg + bp) -> pg [t][XS] ----
    #pragma unroll
    for (int ot = 0; ot < 2; ++ot) {
        const int hb = (wave * 2 + ot) * 16 + q * 4;
        #pragma unroll
        for (int tt = 0; tt < 6; ++tt) {
            const int t = tt * 16 + l16;
            f32x4 s = eacc[ot][tt];
            float sg0 = __fdividef(1.f, 1.f + __expf(-(s[0] + bgv[ot].x * cfac[tt])));
            float sg1 = __fdividef(1.f, 1.f + __expf(-(s[1] + bgv[ot].y * cfac[tt])));
            float sg2 = __fdividef(1.f, 1.f + __expf(-(s[2] + bgv[ot].z * cfac[tt])));
            float sg3 = __fdividef(1.f, 1.f + __expf(-(s[3] + bgv[ot].w * cfac[tt])));
            unsigned u0 = pacc[ot][tt][0], u1 = pacc[ot][tt][1];
            float p0 = (u2f(u0 << 16)         + bp[ot].x) * sg0;
            float p1 = (u2f(u0 & 0xffff0000u) + bp[ot].y) * sg1;
            float p2 = (u2f(u1 << 16)         + bp[ot].z) * sg2;
            float p3 = (u2f(u1 & 0xffff0000u) + bp[ot].w) * sg3;
            union { unsigned u[2]; ushort4 s; } pk;
            pk.u[0] = pack_bf16_2(p0, p1);
            pk.u[1] = pack_bf16_2(p2, p3);
            *(ushort4*)&gpg[t * XS + hb] = pk.s;
        }
    }

    // ---- W_con frags + bias2: issued here, stay in flight across the raw barrier ----
    short8 wc[2][4];
    float4 bias2[2];
    #pragma unroll
    for (int ot = 0; ot < 2; ++ot) {
        const int o = (wave * 2 + ot) * 16;
        const unsigned short* wrc = ws + WS_WCON + (size_t)(o + l16) * H_DIM + q * 8;
        #pragma unroll
        for (int k0 = 0; k0 < 4; ++k0)
            wc[ot][k0] = *(const short8*)(wrc + k0 * 32);
        bias2[ot] = *(const float4*)(b_con + o + q * 4);
    }
    BAR_LGKM();   // cross-wave handoff: pg B-frags span all h (vmem NOT drained)

    // ---- GEMM2: out[o][t] = Wc @ pg^T + b ----
    float* og = out + ((size_t)b * T_DIM * N_DIM + (size_t)n) * H_DIM;
    #pragma unroll
    for (int mt = 0; mt < 6; ++mt) {
        short8 bfr[4];
        const unsigned short* prow = &gpg[(mt * 16 + l16) * XS];
        #pragma unroll
        for (int k0 = 0; k0 < 4; ++k0)
            bfr[k0] = *(const short8*)(prow + k0 * 32 + q * 8);
        const int t = mt * 16 + l16;
        #pragma unroll
        for (int ot = 0; ot < 2; ++ot) {
            f32x4 acc = {0.f, 0.f, 0.f, 0.f};
            #pragma unroll
            for (int k0 = 0; k0 < 4; ++k0)
                acc = __builtin_amdgcn_mfma_f32_16x16x32_bf16(wc[ot][k0], bfr[k0], acc, 0, 0, 0);
            const int o = (wave * 2 + ot) * 16 + q * 4;
            float4 v;
            v.x = acc[0] + bias2[ot].x;
            v.y = acc[1] + bias2[ot].y;
            v.z = acc[2] + bias2[ot].z;
            v.w = acc[3] + bias2[ot].w;
            *(float4*)(og + (size_t)t * NH + o) = v;
        }
    }
}

extern "C" void kernel_launch(void* const* d_in, const int* in_sizes, int n_in,
                              void* d_out, int out_size, void* d_ws, size_t ws_size,
                              hipStream_t stream) {
    const float* x     = (const float*)d_in[0];
    const float* W_exp = (const float*)d_in[1];
    const float* b_exp = (const float*)d_in[2];
    const float* W_con = (const float*)d_in[3];
    const float* b_con = (const float*)d_in[4];
    float* out = (float*)d_out;
    unsigned short* ws = (unsigned short*)d_ws;

    hipLaunchKernelGGL(prep_kernel, dim3(WS_TOTAL / 256), dim3(256), 0, stream,
                       W_exp, W_con, ws);
    hipLaunchKernelGGL(mamba_fused, dim3(B_DIM * N_DIM), dim3(256), 0, stream,
                       x, ws, b_exp, b_con, out);
}